// Round 9
// baseline (234.832 us; speedup 1.0000x reference)
//
#include <hip/hip_runtime.h>
#include <math.h>

#define Bsz 2
#define Ssz 1024
#define Dsz 1024
#define Hn 16
#define DHsz 64
#define QKV3 3072
#define SCALE 0.125f

typedef __bf16 bf16;
typedef bf16 bf16x8 __attribute__((ext_vector_type(8)));
typedef bf16 bf16x4 __attribute__((ext_vector_type(4)));
typedef float f32x4 __attribute__((ext_vector_type(4)));

#define MFMA(a, b, c) __builtin_amdgcn_mfma_f32_16x16x32_bf16(a, b, c, 0, 0, 0)
#define LDT 72

// ---------------------------------------------------------------------------
// casts
// ---------------------------------------------------------------------------
__global__ void cast_hilo(const float* __restrict__ src, bf16* __restrict__ hi,
                          bf16* __restrict__ lo, int n) {
  int idx = (blockIdx.x * 256 + threadIdx.x) * 4;
  if (idx >= n) return;
  float4 v = *(const float4*)(src + idx);
  bf16 h0 = (bf16)v.x, h1 = (bf16)v.y, h2 = (bf16)v.z, h3 = (bf16)v.w;
  bf16x4 hv = {h0, h1, h2, h3};
  bf16x4 lv = {(bf16)(v.x - (float)h0), (bf16)(v.y - (float)h1),
               (bf16)(v.z - (float)h2), (bf16)(v.w - (float)h3)};
  *(bf16x4*)(hi + idx) = hv;
  *(bf16x4*)(lo + idx) = lv;
}

__global__ void cast_hi(const float* __restrict__ src, bf16* __restrict__ hi, int n) {
  int idx = (blockIdx.x * 256 + threadIdx.x) * 4;
  if (idx >= n) return;
  float4 v = *(const float4*)(src + idx);
  bf16x4 hv = {(bf16)v.x, (bf16)v.y, (bf16)v.z, (bf16)v.w};
  *(bf16x4*)(hi + idx) = hv;
}

// kbtt[d][h] = -clip(p_h)*log1p(clip(a_h)*d)
__global__ void kb_table(const float* __restrict__ bias_p, const float* __restrict__ bias_a,
                         float* __restrict__ kbtt) {
  int idx = blockIdx.x * 256 + threadIdx.x;  // 16384
  int d = idx >> 4, h = idx & 15;
  float p = fmaxf(bias_p[h], 0.01f), a = fmaxf(bias_a[h], 0.01f);
  kbtt[idx] = -p * log1pf(a * (float)d);
}

// tk[o][n] = { b1[n] + sum_h w1[n][16+h]*kb(|o-1024|,h),  kb(|o-1024|,n) }
// offset-indexed: o = j - i + 1024  (no abs at use site)
__global__ void tk_table(const float* __restrict__ kbtt, const float* __restrict__ w1,
                         const float* __restrict__ b1, float2* __restrict__ tk) {
  int idx = blockIdx.x * 256 + threadIdx.x;  // 32768
  int o = idx >> 4, n = idx & 15;
  int d = o - 1024; if (d < 0) d = -d; if (d > 1023) d = 1023;
  float t1 = b1[n];
#pragma unroll
  for (int h = 0; h < 16; ++h) t1 += w1[n * 32 + 16 + h] * kbtt[d * 16 + h];
  tk[idx] = make_float2(t1, kbtt[d * 16 + n]);
}

// Precompute dape MFMA weight fragments: wf[0..511]=w1d (hi|lo), wf[512..1023]=w2a
__global__ void wfrag(const float* __restrict__ w1, const float* __restrict__ w2,
                      bf16* __restrict__ wf) {
  int lane = threadIdx.x;  // 64
  int l15 = lane & 15, q8 = (lane >> 4) << 3;
  bf16x8 w1d, w2a;
#pragma unroll
  for (int e = 0; e < 8; ++e) {
    int k = q8 + e;
    if (k < 16) {
      w1d[e] = (bf16)w1[l15 * 32 + k];
    } else {
      float w = w1[l15 * 32 + k - 16];
      w1d[e] = (bf16)(w - (float)(bf16)w);
    }
    w2a[e] = (bf16)w2[l15 * 16 + (k & 15)];
  }
  *(bf16x8*)(wf + lane * 8) = w1d;
  *(bf16x8*)(wf + 512 + lane * 8) = w2a;
}

// ---------------------------------------------------------------------------
// K1: qkv_bf = bf16( x_h @ (w_h+w_l)^T )  2-term MFMA, tile 128x96 -> 512 blocks
// ---------------------------------------------------------------------------
__global__ __launch_bounds__(256, 2) void k1_qkv(const bf16* __restrict__ A,
                                                 const bf16* __restrict__ Bh,
                                                 const bf16* __restrict__ Bl,
                                                 bf16* __restrict__ C) {
  __shared__ __align__(16) bf16 sA[128 * LDT];
  __shared__ __align__(16) bf16 sBh[96 * LDT], sBl[96 * LDT];
  const int tid = threadIdx.x;
  const int lane = tid & 63, wv = tid >> 6;
  const int wr = wv >> 1, wc = wv & 1;
  const int l15 = lane & 15, q8 = (lane >> 4) << 3, q4 = (lane >> 4) << 2;
  const int m0 = blockIdx.y * 128, n0 = blockIdx.x * 96;
  const int r0 = tid >> 3, c8 = (tid & 7) << 3;

  f32x4 acc[4][3];
#pragma unroll
  for (int t = 0; t < 4; ++t)
#pragma unroll
    for (int u = 0; u < 3; ++u)
#pragma unroll
      for (int r = 0; r < 4; ++r) acc[t][u][r] = 0.f;

  bf16x8 rA[4], rBh[3], rBl[3];
#define K1_LOAD(kt)                                                         \
  {                                                                         \
    _Pragma("unroll") for (int c = 0; c < 4; ++c)                           \
      rA[c] = *(const bf16x8*)(A + (size_t)(m0 + c * 32 + r0) * Dsz + (kt) + c8);  \
    _Pragma("unroll") for (int c = 0; c < 3; ++c) {                         \
      rBh[c] = *(const bf16x8*)(Bh + (size_t)(n0 + c * 32 + r0) * Dsz + (kt) + c8); \
      rBl[c] = *(const bf16x8*)(Bl + (size_t)(n0 + c * 32 + r0) * Dsz + (kt) + c8); \
    }                                                                       \
  }

  K1_LOAD(0)
  for (int kt = 0; kt < Dsz; kt += 64) {
    __syncthreads();
#pragma unroll
    for (int c = 0; c < 4; ++c) *(bf16x8*)&sA[(c * 32 + r0) * LDT + c8] = rA[c];
#pragma unroll
    for (int c = 0; c < 3; ++c) {
      *(bf16x8*)&sBh[(c * 32 + r0) * LDT + c8] = rBh[c];
      *(bf16x8*)&sBl[(c * 32 + r0) * LDT + c8] = rBl[c];
    }
    __syncthreads();
    if (kt + 64 < Dsz) K1_LOAD(kt + 64)
#pragma unroll
    for (int ks = 0; ks < 64; ks += 32) {
      bf16x8 fa[4], fbh[3], fbl[3];
#pragma unroll
      for (int t = 0; t < 4; ++t)
        fa[t] = *(const bf16x8*)&sA[(wr * 64 + t * 16 + l15) * LDT + ks + q8];
#pragma unroll
      for (int u = 0; u < 3; ++u) {
        int n = wc * 48 + u * 16 + l15;
        fbh[u] = *(const bf16x8*)&sBh[n * LDT + ks + q8];
        fbl[u] = *(const bf16x8*)&sBl[n * LDT + ks + q8];
      }
#pragma unroll
      for (int t = 0; t < 4; ++t)
#pragma unroll
        for (int u = 0; u < 3; ++u) {
          acc[t][u] = MFMA(fa[t], fbh[u], acc[t][u]);
          acc[t][u] = MFMA(fa[t], fbl[u], acc[t][u]);
        }
    }
  }
#pragma unroll
  for (int t = 0; t < 4; ++t)
#pragma unroll
    for (int u = 0; u < 3; ++u) {
      int col = n0 + wc * 48 + u * 16 + l15;
#pragma unroll
      for (int r = 0; r < 4; ++r) {
        int row = m0 + wr * 64 + t * 16 + q4 + r;
        C[(size_t)row * QKV3 + col] = (bf16)acc[t][u][r];
      }
    }
#undef K1_LOAD
}

// ---------------------------------------------------------------------------
// pack V transposed: v_t[b][h][d][j]
// ---------------------------------------------------------------------------
__global__ void pack_vt(const bf16* __restrict__ qkv, bf16* __restrict__ vt) {
  __shared__ __align__(16) bf16 T[64 * LDT];
  const int tid = threadIdx.x;
  const int bh = blockIdx.y, b = bh >> 4, h = bh & 15;
  const int j0 = blockIdx.x * 64;
#pragma unroll
  for (int c = 0; c < 2; ++c) {
    int lin = c * 256 + tid;
    int jr = lin >> 3, d8 = (lin & 7) << 3;
    bf16x8 v = *(const bf16x8*)(qkv + (size_t)(b * Ssz + j0 + jr) * QKV3 + 2048 + h * DHsz + d8);
#pragma unroll
    for (int e = 0; e < 8; ++e) T[(d8 + e) * LDT + jr] = v[e];
  }
  __syncthreads();
#pragma unroll
  for (int c = 0; c < 2; ++c) {
    int lin = c * 256 + tid;
    int d = lin >> 3, j8 = (lin & 7) << 3;
    bf16x8 o = *(const bf16x8*)&T[d * LDT + j8];
    *(bf16x8*)(vt + ((size_t)(b * Hn + h) * DHsz + d) * Ssz + j0 + j8) = o;
  }
}

// ---------------------------------------------------------------------------
// K2: scores_bf[b][h][i][j] = bf16( SCALE * Q @ K^T )   both batches, one launch
// ---------------------------------------------------------------------------
__global__ __launch_bounds__(256, 3) void k2_qk(const bf16* __restrict__ qkv,
                                                bf16* __restrict__ scores) {
  __shared__ __align__(16) bf16 sA[128 * LDT], sB[128 * LDT];
  const int tid = threadIdx.x;
  const int lane = tid & 63, wv = tid >> 6;
  const int wr = wv >> 1, wc = wv & 1;
  const int l15 = lane & 15, q8 = (lane >> 4) << 3, q4 = (lane >> 4) << 2;
  const int z = blockIdx.z, b = z >> 4, h = z & 15;
  const int i0 = blockIdx.y * 128, j0 = blockIdx.x * 128;
  const bf16* Ab = qkv + (size_t)b * Ssz * QKV3 + h * DHsz;
  const bf16* Bb = Ab + Ssz;
  const int r0 = tid >> 3, c8 = (tid & 7) << 3;
#pragma unroll
  for (int c = 0; c < 4; ++c) {
    int row = c * 32 + r0;
    *(bf16x8*)&sA[row * LDT + c8] = *(const bf16x8*)(Ab + (size_t)(i0 + row) * QKV3 + c8);
    *(bf16x8*)&sB[row * LDT + c8] = *(const bf16x8*)(Bb + (size_t)(j0 + row) * QKV3 + c8);
  }
  __syncthreads();
  f32x4 acc[4][4];
#pragma unroll
  for (int t = 0; t < 4; ++t)
#pragma unroll
    for (int u = 0; u < 4; ++u)
#pragma unroll
      for (int r = 0; r < 4; ++r) acc[t][u][r] = 0.f;
#pragma unroll
  for (int ks = 0; ks < 64; ks += 32) {
    bf16x8 fa[4], fb[4];
#pragma unroll
    for (int t = 0; t < 4; ++t) fa[t] = *(const bf16x8*)&sA[(wr * 64 + t * 16 + l15) * LDT + ks + q8];
#pragma unroll
    for (int u = 0; u < 4; ++u) fb[u] = *(const bf16x8*)&sB[(wc * 64 + u * 16 + l15) * LDT + ks + q8];
#pragma unroll
    for (int t = 0; t < 4; ++t)
#pragma unroll
      for (int u = 0; u < 4; ++u) acc[t][u] = MFMA(fa[t], fb[u], acc[t][u]);
  }
  bf16* dstp = scores + ((size_t)(b * Hn + h) << 20);
#pragma unroll
  for (int t = 0; t < 4; ++t)
#pragma unroll
    for (int u = 0; u < 4; ++u) {
      int col = j0 + wc * 64 + u * 16 + l15;
#pragma unroll
      for (int r = 0; r < 4; ++r) {
        int row = i0 + wr * 64 + t * 16 + q4 + r;
        dstp[((size_t)row << 10) + col] = (bf16)(acc[t][u][r] * SCALE);
      }
    }
}

// ---------------------------------------------------------------------------
// K3: DAPE MLP v3 — straight-line, no barrier, no lgt. In-place bf16.
// Block = (chunk c of 256 j, row i, batch b). Wave owns 64 j, fully independent.
// tk float2 table (offset-indexed, no abs) gives {t1+bias, kb} in one load.
// Logit->exp->bf16 prob composed in registers; per-wave sums via shfl+atomicAdd.
// ---------------------------------------------------------------------------
__device__ __forceinline__ float gelu_fast(float x) {
  float z = fabsf(x) * 0.70710678118654752f;
  float t = __builtin_amdgcn_rcpf(fmaf(0.3275911f, z, 1.0f));
  float poly = t * fmaf(t, fmaf(t, fmaf(t, fmaf(t, 1.061405429f, -1.453152027f),
                                        1.421413741f), -0.284496736f), 0.254829592f);
  float erfa = 1.0f - poly * __expf(-z * z);
  float erfs = copysignf(erfa, x);
  return 0.5f * x * (1.0f + erfs);
}

#define SHS 264  // sH row stride (bf16)

__global__ __launch_bounds__(256, 8) void dape_softmax(bf16* scores,
                                                       const float2* __restrict__ tk,
                                                       const bf16* __restrict__ wf,
                                                       const float* __restrict__ b2,
                                                       float* __restrict__ sums) {
  const int c = blockIdx.x;   // chunk 0..3 (256 j each)
  const int i = blockIdx.y;   // query row
  const int b = blockIdx.z;   // batch
  const int tid = threadIdx.x;
  const int lane = tid & 63, wv = tid >> 6;
  const int l15 = lane & 15, q = lane >> 4;
  const int q8 = q << 3, q4 = q << 2;

  __shared__ bf16 sH[Hn][SHS];                   // 8448 B raw bf16 scores
  __shared__ __align__(16) bf16 hdnS[4][16][40]; // 5120 B (cols 16..31 zeroed)

  const bf16x8 w1d = *(const bf16x8*)(wf + lane * 8);
  const bf16x8 w2a = *(const bf16x8*)(wf + 512 + lane * 8);
  const float bias2 = b2[l15];

  if (lane < 32) {
    int row = lane >> 1, col = 16 + (lane & 1) * 8;
    *(bf16x8*)&hdnS[wv][row][col] = (bf16x8){};
  }

  // ---- stage this wave's 64-j slice of all 16 head rows (bf16x8 copies) ----
  const int jw = wv * 64;
  const bf16* srow = scores + ((size_t)(b * Hn) << 20) + ((size_t)i << 10) + c * 256;
#pragma unroll
  for (int t = 0; t < 2; ++t) {
    int h = t * 8 + (lane >> 3);
    int col = jw + (lane & 7) * 8;
    *(bf16x8*)&sH[h][col] = *(const bf16x8*)(srow + ((size_t)h << 20) + col);
  }
  // no barrier anywhere: waves are column-disjoint

  // tk pointer: o = (global j) - i + 1024, linear in j
  const float2* tkp = tk + ((size_t)(c * 256 + jw + q4 - i + 1024) << 4) + l15;
  bf16* dsth = scores + ((size_t)(b * Hn + l15) << 20) + ((size_t)i << 10) + c * 256;
  float s_acc = 0.f;

  for (int jt = 0; jt < 4; ++jt) {
    const int j0c = jw + jt * 16;
    // layer-1 A: raw bf16 gather (head dup across k-halves)
    bf16x8 a1;
#pragma unroll
    for (int e = 0; e < 8; ++e) a1[e] = sH[(q8 + e) & 15][j0c + l15];
    float2 tkv[4];
#pragma unroll
    for (int r = 0; r < 4; ++r) tkv[r] = tkp[r * 16];
    f32x4 c1 = {tkv[0].x, tkv[1].x, tkv[2].x, tkv[3].x};
    c1 = MFMA(a1, w1d, c1);
#pragma unroll
    for (int r = 0; r < 4; ++r) hdnS[wv][q4 + r][l15] = (bf16)gelu_fast(c1[r]);
    bf16x8 a2 = *(const bf16x8*)&hdnS[wv][l15][q8];
    f32x4 c2 = {bias2, bias2, bias2, bias2};
    c2 = MFMA(a2, w2a, c2);
    // compose logit -> exp -> bf16 prob, all in registers (lane: h=l15, 4 j's)
    bf16x4 sc4 = *(const bf16x4*)&sH[l15][j0c + q4];
    bf16x4 pv;
#pragma unroll
    for (int r = 0; r < 4; ++r) {
      float lg = (float)sc4[r] + tkv[r].y + c2[r];
      float e = __expf(lg);
      pv[r] = (bf16)e;
      s_acc += e;
    }
    *(bf16x4*)(dsth + j0c + q4) = pv;
    tkp += 256;  // +16 o
  }

  // per-wave head-sums: reduce over quads, one atomic per head
  s_acc += __shfl_xor(s_acc, 16, 64);
  s_acc += __shfl_xor(s_acc, 32, 64);
  if (lane < 16) atomicAdd(&sums[(((b << 10) + i) << 4) + lane], s_acc);
}

// ---------------------------------------------------------------------------
// K4: aout = (P_un @ V) / sums[b][i][h]   (via v_t), per (i-tile, h, b)
// ---------------------------------------------------------------------------
__global__ __launch_bounds__(256, 4) void k4_av(const bf16* __restrict__ attn,
                                                const bf16* __restrict__ vt,
                                                const float* __restrict__ sums,
                                                bf16* __restrict__ aout) {
  __shared__ __align__(16) bf16 sA[64 * LDT], sB[64 * LDT];
  const int tid = threadIdx.x;
  const int lane = tid & 63, wv = tid >> 6;
  const int wr = wv >> 1, wc = wv & 1;
  const int l15 = lane & 15, q8 = (lane >> 4) << 3, q4 = (lane >> 4) << 2;
  const int i0 = blockIdx.x * 64, h = blockIdx.y, b = blockIdx.z;
  const bf16* Ab = attn + ((size_t)(b * Hn + h) << 20) + ((size_t)i0 << 10);
  const bf16* Bb = vt + (size_t)(b * Hn + h) * DHsz * Ssz;
  const int r0 = tid >> 3, c8 = (tid & 7) << 3;
  f32x4 acc[2][2];
#pragma unroll
  for (int t = 0; t < 2; ++t)
#pragma unroll
    for (int u = 0; u < 2; ++u)
#pragma unroll
      for (int r = 0; r < 4; ++r) acc[t][u][r] = 0.f;
  bf16x8 rA[2], rB[2];
#define K4_LOAD(kt)                                               \
  {                                                               \
    _Pragma("unroll") for (int c = 0; c < 2; ++c) {               \
      int row = c * 32 + r0;                                      \
      rA[c] = *(const bf16x8*)(Ab + ((size_t)row << 10) + (kt) + c8); \
      rB[c] = *(const bf16x8*)(Bb + ((size_t)row << 10) + (kt) + c8); \
    }                                                             \
  }
  K4_LOAD(0)
  for (int kt = 0; kt < Ssz; kt += 64) {
    __syncthreads();
#pragma unroll
    for (int c = 0; c < 2; ++c) {
      int row = c * 32 + r0;
      *(bf16x8*)&sA[row * LDT + c8] = rA[c];
      *(bf16x8*)&sB[row * LDT + c8] = rB[c];
    }
    __syncthreads();
    if (kt + 64 < Ssz) K4_LOAD(kt + 64)
#pragma unroll
    for (int ks = 0; ks < 64; ks += 32) {
      bf16x8 fa[2], fb[2];
#pragma unroll
      for (int t = 0; t < 2; ++t) fa[t] = *(const bf16x8*)&sA[(wr * 32 + t * 16 + l15) * LDT + ks + q8];
#pragma unroll
      for (int u = 0; u < 2; ++u) fb[u] = *(const bf16x8*)&sB[(wc * 32 + u * 16 + l15) * LDT + ks + q8];
#pragma unroll
      for (int t = 0; t < 2; ++t)
#pragma unroll
        for (int u = 0; u < 2; ++u) acc[t][u] = MFMA(fa[t], fb[u], acc[t][u]);
    }
  }
#pragma unroll
  for (int t = 0; t < 2; ++t)
#pragma unroll
    for (int r = 0; r < 4; ++r) {
      int row = i0 + wr * 32 + t * 16 + q4 + r;
      float inv = 1.f / sums[(((b << 10) + row) << 4) + h];
#pragma unroll
      for (int u = 0; u < 2; ++u) {
        int d = wc * 32 + u * 16 + l15;
        aout[(size_t)(b * Ssz + row) * Dsz + h * DHsz + d] = (bf16)(acc[t][u][r] * inv);
      }
    }
#undef K4_LOAD
}

// ---------------------------------------------------------------------------
// K5: out = aout_bf @ (ow_h+ow_l)^T  2-term, fp32 out, tile 64x64 -> 512 blocks
// ---------------------------------------------------------------------------
__global__ __launch_bounds__(256, 3) void k5_out(const bf16* __restrict__ A,
                                                 const bf16* __restrict__ Bh,
                                                 const bf16* __restrict__ Bl,
                                                 float* __restrict__ C) {
  __shared__ __align__(16) bf16 sA[64 * LDT], sBh[64 * LDT], sBl[64 * LDT];
  const int tid = threadIdx.x;
  const int lane = tid & 63, wv = tid >> 6;
  const int wr = wv >> 1, wc = wv & 1;
  const int l15 = lane & 15, q8 = (lane >> 4) << 3, q4 = (lane >> 4) << 2;
  const int m0 = blockIdx.y * 64, n0 = blockIdx.x * 64;
  const int r0 = tid >> 3, c8 = (tid & 7) << 3;
  f32x4 acc[2][2];
#pragma unroll
  for (int t = 0; t < 2; ++t)
#pragma unroll
    for (int u = 0; u < 2; ++u)
#pragma unroll
      for (int r = 0; r < 4; ++r) acc[t][u][r] = 0.f;
  bf16x8 rA[2], rBh[2], rBl[2];
#define K5_LOAD(kt)                                                       \
  {                                                                       \
    _Pragma("unroll") for (int c = 0; c < 2; ++c) {                       \
      int row = c * 32 + r0;                                              \
      rA[c] = *(const bf16x8*)(A + (size_t)(m0 + row) * Dsz + (kt) + c8);   \
      rBh[c] = *(const bf16x8*)(Bh + (size_t)(n0 + row) * Dsz + (kt) + c8); \
      rBl[c] = *(const bf16x8*)(Bl + (size_t)(n0 + row) * Dsz + (kt) + c8); \
    }                                                                     \
  }
  K5_LOAD(0)
  for (int kt = 0; kt < Dsz; kt += 64) {
    __syncthreads();
#pragma unroll
    for (int c = 0; c < 2; ++c) {
      int row = c * 32 + r0;
      *(bf16x8*)&sA[row * LDT + c8] = rA[c];
      *(bf16x8*)&sBh[row * LDT + c8] = rBh[c];
      *(bf16x8*)&sBl[row * LDT + c8] = rBl[c];
    }
    __syncthreads();
    if (kt + 64 < Dsz) K5_LOAD(kt + 64)
#pragma unroll
    for (int ks = 0; ks < 64; ks += 32) {
      bf16x8 fa[2], fbh[2], fbl[2];
#pragma unroll
      for (int t = 0; t < 2; ++t) fa[t] = *(const bf16x8*)&sA[(wr * 32 + t * 16 + l15) * LDT + ks + q8];
#pragma unroll
      for (int u = 0; u < 2; ++u) {
        int n = wc * 32 + u * 16 + l15;
        fbh[u] = *(const bf16x8*)&sBh[n * LDT + ks + q8];
        fbl[u] = *(const bf16x8*)&sBl[n * LDT + ks + q8];
      }
#pragma unroll
      for (int t = 0; t < 2; ++t)
#pragma unroll
        for (int u = 0; u < 2; ++u) {
          acc[t][u] = MFMA(fa[t], fbh[u], acc[t][u]);
          acc[t][u] = MFMA(fa[t], fbl[u], acc[t][u]);
        }
    }
  }
#pragma unroll
  for (int t = 0; t < 2; ++t)
#pragma unroll
    for (int u = 0; u < 2; ++u) {
      int col = n0 + wc * 32 + u * 16 + l15;
#pragma unroll
      for (int r = 0; r < 4; ++r) {
        int row = m0 + wr * 32 + t * 16 + q4 + r;
        C[(size_t)row * Dsz + col] = acc[t][u][r];
      }
    }
#undef K5_LOAD
}

// ---------------------------------------------------------------------------
extern "C" void kernel_launch(void* const* d_in, const int* in_sizes, int n_in,
                              void* d_out, int out_size, void* d_ws, size_t ws_size,
                              hipStream_t stream) {
  const float* x      = (const float*)d_in[0];
  const float* qkv_w  = (const float*)d_in[1];
  const float* out_w  = (const float*)d_in[2];
  const float* bias_p = (const float*)d_in[3];
  const float* bias_a = (const float*)d_in[4];
  const float* w1     = (const float*)d_in[5];
  const float* b1     = (const float*)d_in[6];
  const float* w2     = (const float*)d_in[7];
  const float* b2     = (const float*)d_in[8];
  float* out = (float*)d_out;

  // ws layout (bytes). scores (64 MB) ALIASES x_h/w_h/w_l (dead after k1).
  char* ws = (char*)d_ws;
  const size_t MB = 1ull << 20;
  bf16* ow_h   = (bf16*)(ws + 0 * MB);            // 2 MB
  bf16* ow_l   = (bf16*)(ws + 2 * MB);            // 2 MB
  bf16* qkv_bf = (bf16*)(ws + 4 * MB);            // 12 MB
  bf16* v_t    = (bf16*)(ws + 16 * MB);           // 4 MB
  bf16* aout   = (bf16*)(ws + 20 * MB);           // 4 MB
  float* kbtt  = (float*)(ws + 24 * MB);          // 64 KB
  float* sums  = (float*)(ws + 24 * MB + 65536);  // 128 KB [b][i][h]
  bf16* wf     = (bf16*)(ws + 24 * MB + 196608);  // 2 KB
  float2* tk   = (float2*)(ws + 24 * MB + 262144);// 256 KB [o][n]
  bf16* x_h    = (bf16*)(ws + 25 * MB);           // 4 MB   (dead after k1)
  bf16* w_h    = (bf16*)(ws + 29 * MB);           // 6 MB   (dead after k1)
  bf16* w_l    = (bf16*)(ws + 35 * MB);           // 6 MB   (dead after k1)
  bf16* sc_bf  = (bf16*)(ws + 25 * MB);           // 64 MB, ends at 89 MB

  cast_hi<<<2048, 256, 0, stream>>>(x, x_h, Bsz * Ssz * Dsz);
  cast_hilo<<<3072, 256, 0, stream>>>(qkv_w, w_h, w_l, QKV3 * Dsz);
  cast_hilo<<<1024, 256, 0, stream>>>(out_w, ow_h, ow_l, Dsz * Dsz);
  kb_table<<<64, 256, 0, stream>>>(bias_p, bias_a, kbtt);
  tk_table<<<128, 256, 0, stream>>>(kbtt, w1, b1, tk);
  wfrag<<<1, 64, 0, stream>>>(w1, w2, wf);
  hipMemsetAsync(sums, 0, Bsz * Ssz * Hn * sizeof(float), stream);

  k1_qkv<<<dim3(QKV3 / 96, (Bsz * Ssz) / 128), 256, 0, stream>>>(x_h, w_h, w_l, qkv_bf);
  pack_vt<<<dim3(Ssz / 64, Bsz * Hn), 256, 0, stream>>>(qkv_bf, v_t);

  k2_qk<<<dim3(Ssz / 128, Ssz / 128, Bsz * Hn), 256, 0, stream>>>(qkv_bf, sc_bf);
  dape_softmax<<<dim3(4, Ssz, Bsz), 256, 0, stream>>>(sc_bf, tk, wf, b2, sums);
  k4_av<<<dim3(Ssz / 64, Hn, Bsz), 256, 0, stream>>>(sc_bf, v_t, sums, aout);

  k5_out<<<dim3(Dsz / 64, (Bsz * Ssz) / 64), 256, 0, stream>>>(aout, ow_h, ow_l, out);
}

// Round 10
// 217.586 us; speedup vs baseline: 1.0793x; 1.0793x over previous
//
#include <hip/hip_runtime.h>
#include <math.h>

#define Bsz 2
#define Ssz 1024
#define Dsz 1024
#define Hn 16
#define DHsz 64
#define QKV3 3072
#define SCALE 0.125f

typedef __bf16 bf16;
typedef bf16 bf16x8 __attribute__((ext_vector_type(8)));
typedef bf16 bf16x4 __attribute__((ext_vector_type(4)));
typedef float f32x4 __attribute__((ext_vector_type(4)));

#define MFMA(a, b, c) __builtin_amdgcn_mfma_f32_16x16x32_bf16(a, b, c, 0, 0, 0)
#define LDT 72

// ---------------------------------------------------------------------------
// casts
// ---------------------------------------------------------------------------
__global__ void cast_hilo(const float* __restrict__ src, bf16* __restrict__ hi,
                          bf16* __restrict__ lo, int n) {
  int idx = (blockIdx.x * 256 + threadIdx.x) * 4;
  if (idx >= n) return;
  float4 v = *(const float4*)(src + idx);
  bf16 h0 = (bf16)v.x, h1 = (bf16)v.y, h2 = (bf16)v.z, h3 = (bf16)v.w;
  bf16x4 hv = {h0, h1, h2, h3};
  bf16x4 lv = {(bf16)(v.x - (float)h0), (bf16)(v.y - (float)h1),
               (bf16)(v.z - (float)h2), (bf16)(v.w - (float)h3)};
  *(bf16x4*)(hi + idx) = hv;
  *(bf16x4*)(lo + idx) = lv;
}

__global__ void cast_hi(const float* __restrict__ src, bf16* __restrict__ hi, int n) {
  int idx = (blockIdx.x * 256 + threadIdx.x) * 4;
  if (idx >= n) return;
  float4 v = *(const float4*)(src + idx);
  bf16x4 hv = {(bf16)v.x, (bf16)v.y, (bf16)v.z, (bf16)v.w};
  *(bf16x4*)(hi + idx) = hv;
}

// kbtt[d][h] = -clip(p_h)*log1p(clip(a_h)*d)
__global__ void kb_table(const float* __restrict__ bias_p, const float* __restrict__ bias_a,
                         float* __restrict__ kbtt) {
  int idx = blockIdx.x * 256 + threadIdx.x;  // 16384
  int d = idx >> 4, h = idx & 15;
  float p = fmaxf(bias_p[h], 0.01f), a = fmaxf(bias_a[h], 0.01f);
  kbtt[idx] = -p * log1pf(a * (float)d);
}

// tk[o][n] = { b1[n] + sum_h w1[n][16+h]*kb(|o-1024|,h),  kb(|o-1024|,n) }
// offset-indexed: o = j - i + 1024  (no abs at use site)
__global__ void tk_table(const float* __restrict__ kbtt, const float* __restrict__ w1,
                         const float* __restrict__ b1, float2* __restrict__ tk) {
  int idx = blockIdx.x * 256 + threadIdx.x;  // 32768
  int o = idx >> 4, n = idx & 15;
  int d = o - 1024; if (d < 0) d = -d; if (d > 1023) d = 1023;
  float t1 = b1[n];
#pragma unroll
  for (int h = 0; h < 16; ++h) t1 += w1[n * 32 + 16 + h] * kbtt[d * 16 + h];
  tk[idx] = make_float2(t1, kbtt[d * 16 + n]);
}

// Precompute dape MFMA weight fragments: wf[0..511]=w1d (hi|lo), wf[512..1023]=w2a
__global__ void wfrag(const float* __restrict__ w1, const float* __restrict__ w2,
                      bf16* __restrict__ wf) {
  int lane = threadIdx.x;  // 64
  int l15 = lane & 15, q8 = (lane >> 4) << 3;
  bf16x8 w1d, w2a;
#pragma unroll
  for (int e = 0; e < 8; ++e) {
    int k = q8 + e;
    if (k < 16) {
      w1d[e] = (bf16)w1[l15 * 32 + k];
    } else {
      float w = w1[l15 * 32 + k - 16];
      w1d[e] = (bf16)(w - (float)(bf16)w);
    }
    w2a[e] = (bf16)w2[l15 * 16 + (k & 15)];
  }
  *(bf16x8*)(wf + lane * 8) = w1d;
  *(bf16x8*)(wf + 512 + lane * 8) = w2a;
}

// ---------------------------------------------------------------------------
// K1: qkv_bf = bf16( x_h @ (w_h+w_l)^T )  2-term MFMA, tile 128x96 -> 512 blocks
// ---------------------------------------------------------------------------
__global__ __launch_bounds__(256, 2) void k1_qkv(const bf16* __restrict__ A,
                                                 const bf16* __restrict__ Bh,
                                                 const bf16* __restrict__ Bl,
                                                 bf16* __restrict__ C) {
  __shared__ __align__(16) bf16 sA[128 * LDT];
  __shared__ __align__(16) bf16 sBh[96 * LDT], sBl[96 * LDT];
  const int tid = threadIdx.x;
  const int lane = tid & 63, wv = tid >> 6;
  const int wr = wv >> 1, wc = wv & 1;
  const int l15 = lane & 15, q8 = (lane >> 4) << 3, q4 = (lane >> 4) << 2;
  const int m0 = blockIdx.y * 128, n0 = blockIdx.x * 96;
  const int r0 = tid >> 3, c8 = (tid & 7) << 3;

  f32x4 acc[4][3];
#pragma unroll
  for (int t = 0; t < 4; ++t)
#pragma unroll
    for (int u = 0; u < 3; ++u)
#pragma unroll
      for (int r = 0; r < 4; ++r) acc[t][u][r] = 0.f;

  bf16x8 rA[4], rBh[3], rBl[3];
#define K1_LOAD(kt)                                                         \
  {                                                                         \
    _Pragma("unroll") for (int c = 0; c < 4; ++c)                           \
      rA[c] = *(const bf16x8*)(A + (size_t)(m0 + c * 32 + r0) * Dsz + (kt) + c8);  \
    _Pragma("unroll") for (int c = 0; c < 3; ++c) {                         \
      rBh[c] = *(const bf16x8*)(Bh + (size_t)(n0 + c * 32 + r0) * Dsz + (kt) + c8); \
      rBl[c] = *(const bf16x8*)(Bl + (size_t)(n0 + c * 32 + r0) * Dsz + (kt) + c8); \
    }                                                                       \
  }

  K1_LOAD(0)
  for (int kt = 0; kt < Dsz; kt += 64) {
    __syncthreads();
#pragma unroll
    for (int c = 0; c < 4; ++c) *(bf16x8*)&sA[(c * 32 + r0) * LDT + c8] = rA[c];
#pragma unroll
    for (int c = 0; c < 3; ++c) {
      *(bf16x8*)&sBh[(c * 32 + r0) * LDT + c8] = rBh[c];
      *(bf16x8*)&sBl[(c * 32 + r0) * LDT + c8] = rBl[c];
    }
    __syncthreads();
    if (kt + 64 < Dsz) K1_LOAD(kt + 64)
#pragma unroll
    for (int ks = 0; ks < 64; ks += 32) {
      bf16x8 fa[4], fbh[3], fbl[3];
#pragma unroll
      for (int t = 0; t < 4; ++t)
        fa[t] = *(const bf16x8*)&sA[(wr * 64 + t * 16 + l15) * LDT + ks + q8];
#pragma unroll
      for (int u = 0; u < 3; ++u) {
        int n = wc * 48 + u * 16 + l15;
        fbh[u] = *(const bf16x8*)&sBh[n * LDT + ks + q8];
        fbl[u] = *(const bf16x8*)&sBl[n * LDT + ks + q8];
      }
#pragma unroll
      for (int t = 0; t < 4; ++t)
#pragma unroll
        for (int u = 0; u < 3; ++u) {
          acc[t][u] = MFMA(fa[t], fbh[u], acc[t][u]);
          acc[t][u] = MFMA(fa[t], fbl[u], acc[t][u]);
        }
    }
  }
#pragma unroll
  for (int t = 0; t < 4; ++t)
#pragma unroll
    for (int u = 0; u < 3; ++u) {
      int col = n0 + wc * 48 + u * 16 + l15;
#pragma unroll
      for (int r = 0; r < 4; ++r) {
        int row = m0 + wr * 64 + t * 16 + q4 + r;
        C[(size_t)row * QKV3 + col] = (bf16)acc[t][u][r];
      }
    }
#undef K1_LOAD
}

// ---------------------------------------------------------------------------
// pack V transposed: v_t[b][h][d][j]
// ---------------------------------------------------------------------------
__global__ void pack_vt(const bf16* __restrict__ qkv, bf16* __restrict__ vt) {
  __shared__ __align__(16) bf16 T[64 * LDT];
  const int tid = threadIdx.x;
  const int bh = blockIdx.y, b = bh >> 4, h = bh & 15;
  const int j0 = blockIdx.x * 64;
#pragma unroll
  for (int c = 0; c < 2; ++c) {
    int lin = c * 256 + tid;
    int jr = lin >> 3, d8 = (lin & 7) << 3;
    bf16x8 v = *(const bf16x8*)(qkv + (size_t)(b * Ssz + j0 + jr) * QKV3 + 2048 + h * DHsz + d8);
#pragma unroll
    for (int e = 0; e < 8; ++e) T[(d8 + e) * LDT + jr] = v[e];
  }
  __syncthreads();
#pragma unroll
  for (int c = 0; c < 2; ++c) {
    int lin = c * 256 + tid;
    int d = lin >> 3, j8 = (lin & 7) << 3;
    bf16x8 o = *(const bf16x8*)&T[d * LDT + j8];
    *(bf16x8*)(vt + ((size_t)(b * Hn + h) * DHsz + d) * Ssz + j0 + j8) = o;
  }
}

// ---------------------------------------------------------------------------
// K2: scores_bf[b][h][i][j] = bf16( SCALE * Q @ K^T )   both batches, one launch
// ---------------------------------------------------------------------------
__global__ __launch_bounds__(256, 3) void k2_qk(const bf16* __restrict__ qkv,
                                                bf16* __restrict__ scores) {
  __shared__ __align__(16) bf16 sA[128 * LDT], sB[128 * LDT];
  const int tid = threadIdx.x;
  const int lane = tid & 63, wv = tid >> 6;
  const int wr = wv >> 1, wc = wv & 1;
  const int l15 = lane & 15, q8 = (lane >> 4) << 3, q4 = (lane >> 4) << 2;
  const int z = blockIdx.z, b = z >> 4, h = z & 15;
  const int i0 = blockIdx.y * 128, j0 = blockIdx.x * 128;
  const bf16* Ab = qkv + (size_t)b * Ssz * QKV3 + h * DHsz;
  const bf16* Bb = Ab + Ssz;
  const int r0 = tid >> 3, c8 = (tid & 7) << 3;
#pragma unroll
  for (int c = 0; c < 4; ++c) {
    int row = c * 32 + r0;
    *(bf16x8*)&sA[row * LDT + c8] = *(const bf16x8*)(Ab + (size_t)(i0 + row) * QKV3 + c8);
    *(bf16x8*)&sB[row * LDT + c8] = *(const bf16x8*)(Bb + (size_t)(j0 + row) * QKV3 + c8);
  }
  __syncthreads();
  f32x4 acc[4][4];
#pragma unroll
  for (int t = 0; t < 4; ++t)
#pragma unroll
    for (int u = 0; u < 4; ++u)
#pragma unroll
      for (int r = 0; r < 4; ++r) acc[t][u][r] = 0.f;
#pragma unroll
  for (int ks = 0; ks < 64; ks += 32) {
    bf16x8 fa[4], fb[4];
#pragma unroll
    for (int t = 0; t < 4; ++t) fa[t] = *(const bf16x8*)&sA[(wr * 64 + t * 16 + l15) * LDT + ks + q8];
#pragma unroll
    for (int u = 0; u < 4; ++u) fb[u] = *(const bf16x8*)&sB[(wc * 64 + u * 16 + l15) * LDT + ks + q8];
#pragma unroll
    for (int t = 0; t < 4; ++t)
#pragma unroll
      for (int u = 0; u < 4; ++u) acc[t][u] = MFMA(fa[t], fb[u], acc[t][u]);
  }
  bf16* dstp = scores + ((size_t)(b * Hn + h) << 20);
#pragma unroll
  for (int t = 0; t < 4; ++t)
#pragma unroll
    for (int u = 0; u < 4; ++u) {
      int col = j0 + wc * 64 + u * 16 + l15;
#pragma unroll
      for (int r = 0; r < 4; ++r) {
        int row = i0 + wr * 64 + t * 16 + q4 + r;
        dstp[((size_t)row << 10) + col] = (bf16)(acc[t][u][r] * SCALE);
      }
    }
}

// ---------------------------------------------------------------------------
// K3: DAPE MLP v4 — r8 structure (lgt + contiguous-write exp phase) + tk table.
// Block = (chunk c of 256 j, row i, batch b). Wave owns 64 j. One barrier.
// ---------------------------------------------------------------------------
__device__ __forceinline__ float gelu_fast(float x) {
  float z = fabsf(x) * 0.70710678118654752f;
  float t = __builtin_amdgcn_rcpf(fmaf(0.3275911f, z, 1.0f));
  float poly = t * fmaf(t, fmaf(t, fmaf(t, fmaf(t, 1.061405429f, -1.453152027f),
                                        1.421413741f), -0.284496736f), 0.254829592f);
  float erfa = 1.0f - poly * __expf(-z * z);
  float erfs = copysignf(erfa, x);
  return 0.5f * x * (1.0f + erfs);
}

#define SHS 264  // sH row stride (bf16)
#define LGS 264  // lgt row stride (fp32)

__global__ __launch_bounds__(256, 5) void dape_softmax(bf16* scores,
                                                       const float2* __restrict__ tk,
                                                       const bf16* __restrict__ wf,
                                                       const float* __restrict__ b2,
                                                       float* __restrict__ sums) {
  const int c = blockIdx.x;   // chunk 0..3 (256 j each)
  const int i = blockIdx.y;   // query row
  const int b = blockIdx.z;   // batch
  const int tid = threadIdx.x;
  const int lane = tid & 63, wv = tid >> 6;
  const int l15 = lane & 15, q = lane >> 4;
  const int q8 = q << 3, q4 = q << 2;

  __shared__ bf16 sH[Hn][SHS];                   // 8448 B raw bf16 scores
  __shared__ float lgt[Hn][LGS];                 // 16896 B logits
  __shared__ __align__(16) bf16 hdnS[4][16][40]; // 5120 B (cols 16..31 zeroed)

  const bf16x8 w1d = *(const bf16x8*)(wf + lane * 8);
  const bf16x8 w2a = *(const bf16x8*)(wf + 512 + lane * 8);
  const float bias2 = b2[l15];

  if (lane < 32) {
    int row = lane >> 1, col = 16 + (lane & 1) * 8;
    *(bf16x8*)&hdnS[wv][row][col] = (bf16x8){};
  }

  // ---- stage this wave's 64-j slice of all 16 head rows (bf16x8 copies) ----
  const int jw = wv * 64;
  const bf16* srow = scores + ((size_t)(b * Hn) << 20) + ((size_t)i << 10) + c * 256;
#pragma unroll
  for (int t = 0; t < 2; ++t) {
    int h = t * 8 + (lane >> 3);
    int col = jw + (lane & 7) * 8;
    *(bf16x8*)&sH[h][col] = *(const bf16x8*)(srow + ((size_t)h << 20) + col);
  }
  // no barrier: each wave touches only its own j-columns until the exp phase

  // tk pointer: o = (global j) - i + 1024, linear in j
  const float2* tkp = tk + ((size_t)(c * 256 + jw + q4 - i + 1024) << 4) + l15;

  for (int jt = 0; jt < 4; ++jt) {
    const int j0c = jw + jt * 16;
    // layer-1 A: raw bf16 gather (head dup across k-halves)
    bf16x8 a1;
#pragma unroll
    for (int e = 0; e < 8; ++e) a1[e] = sH[(q8 + e) & 15][j0c + l15];
    float2 tkv[4];
#pragma unroll
    for (int r = 0; r < 4; ++r) tkv[r] = tkp[r * 16];
    f32x4 c1 = {tkv[0].x, tkv[1].x, tkv[2].x, tkv[3].x};
    c1 = MFMA(a1, w1d, c1);
#pragma unroll
    for (int r = 0; r < 4; ++r) hdnS[wv][q4 + r][l15] = (bf16)gelu_fast(c1[r]);
    bf16x8 a2 = *(const bf16x8*)&hdnS[wv][l15][q8];
    f32x4 c2 = {bias2, bias2, bias2, bias2};
    c2 = MFMA(a2, w2a, c2);
    // logits: score + kb + refine, pure LDS write (lane owns h=l15, 4 j's)
    bf16x4 sc4 = *(const bf16x4*)&sH[l15][j0c + q4];
    f32x4 lg;
#pragma unroll
    for (int r = 0; r < 4; ++r) lg[r] = (float)sc4[r] + tkv[r].y + c2[r];
    *(f32x4*)&lgt[l15][j0c + q4] = lg;
    tkp += 256;  // +16 o
  }
  __syncthreads();

  // ---- exp (no max-sub; logits bounded) + partial sums, contiguous writes ----
#pragma unroll
  for (int hh = 0; hh < 4; ++hh) {
    const int h = wv * 4 + hh;
    f32x4 v0 = *(const f32x4*)&lgt[h][lane * 4];
    float s = 0.f;
#pragma unroll
    for (int e = 0; e < 4; ++e) { v0[e] = __expf(v0[e]); s += v0[e]; }
#pragma unroll
    for (int off = 32; off > 0; off >>= 1) s += __shfl_xor(s, off, 64);
    bf16* dst = scores + ((size_t)(b * Hn + h) << 20) + ((size_t)i << 10) + c * 256;
    bf16x4 p0 = {(bf16)v0[0], (bf16)v0[1], (bf16)v0[2], (bf16)v0[3]};
    *(bf16x4*)(dst + lane * 4) = p0;
    if (lane == 0) sums[((((b << 10) + i) << 4) + h) * 4 + c] = s;
  }
}

// ---------------------------------------------------------------------------
// K4: aout = (P_un @ V) / sum(chunks)   (via v_t), per (i-tile, h, b)
// ---------------------------------------------------------------------------
__global__ __launch_bounds__(256, 4) void k4_av(const bf16* __restrict__ attn,
                                                const bf16* __restrict__ vt,
                                                const float* __restrict__ sums,
                                                bf16* __restrict__ aout) {
  __shared__ __align__(16) bf16 sA[64 * LDT], sB[64 * LDT];
  const int tid = threadIdx.x;
  const int lane = tid & 63, wv = tid >> 6;
  const int wr = wv >> 1, wc = wv & 1;
  const int l15 = lane & 15, q8 = (lane >> 4) << 3, q4 = (lane >> 4) << 2;
  const int i0 = blockIdx.x * 64, h = blockIdx.y, b = blockIdx.z;
  const bf16* Ab = attn + ((size_t)(b * Hn + h) << 20) + ((size_t)i0 << 10);
  const bf16* Bb = vt + (size_t)(b * Hn + h) * DHsz * Ssz;
  const int r0 = tid >> 3, c8 = (tid & 7) << 3;
  f32x4 acc[2][2];
#pragma unroll
  for (int t = 0; t < 2; ++t)
#pragma unroll
    for (int u = 0; u < 2; ++u)
#pragma unroll
      for (int r = 0; r < 4; ++r) acc[t][u][r] = 0.f;
  bf16x8 rA[2], rB[2];
#define K4_LOAD(kt)                                               \
  {                                                               \
    _Pragma("unroll") for (int c = 0; c < 2; ++c) {               \
      int row = c * 32 + r0;                                      \
      rA[c] = *(const bf16x8*)(Ab + ((size_t)row << 10) + (kt) + c8); \
      rB[c] = *(const bf16x8*)(Bb + ((size_t)row << 10) + (kt) + c8); \
    }                                                             \
  }
  K4_LOAD(0)
  for (int kt = 0; kt < Ssz; kt += 64) {
    __syncthreads();
#pragma unroll
    for (int c = 0; c < 2; ++c) {
      int row = c * 32 + r0;
      *(bf16x8*)&sA[row * LDT + c8] = rA[c];
      *(bf16x8*)&sB[row * LDT + c8] = rB[c];
    }
    __syncthreads();
    if (kt + 64 < Ssz) K4_LOAD(kt + 64)
#pragma unroll
    for (int ks = 0; ks < 64; ks += 32) {
      bf16x8 fa[2], fb[2];
#pragma unroll
      for (int t = 0; t < 2; ++t) fa[t] = *(const bf16x8*)&sA[(wr * 32 + t * 16 + l15) * LDT + ks + q8];
#pragma unroll
      for (int u = 0; u < 2; ++u) fb[u] = *(const bf16x8*)&sB[(wc * 32 + u * 16 + l15) * LDT + ks + q8];
#pragma unroll
      for (int t = 0; t < 2; ++t)
#pragma unroll
        for (int u = 0; u < 2; ++u) acc[t][u] = MFMA(fa[t], fb[u], acc[t][u]);
    }
  }
#pragma unroll
  for (int t = 0; t < 2; ++t)
#pragma unroll
    for (int r = 0; r < 4; ++r) {
      int row = i0 + wr * 32 + t * 16 + q4 + r;
      f32x4 sv = *(const f32x4*)&sums[((((b << 10) + row) << 4) + h) * 4];
      float inv = 1.f / (sv[0] + sv[1] + sv[2] + sv[3]);
#pragma unroll
      for (int u = 0; u < 2; ++u) {
        int d = wc * 32 + u * 16 + l15;
        aout[(size_t)(b * Ssz + row) * Dsz + h * DHsz + d] = (bf16)(acc[t][u][r] * inv);
      }
    }
#undef K4_LOAD
}

// ---------------------------------------------------------------------------
// K5: out = aout_bf @ (ow_h+ow_l)^T  2-term, fp32 out, tile 64x64 -> 512 blocks
// ---------------------------------------------------------------------------
__global__ __launch_bounds__(256, 3) void k5_out(const bf16* __restrict__ A,
                                                 const bf16* __restrict__ Bh,
                                                 const bf16* __restrict__ Bl,
                                                 float* __restrict__ C) {
  __shared__ __align__(16) bf16 sA[64 * LDT], sBh[64 * LDT], sBl[64 * LDT];
  const int tid = threadIdx.x;
  const int lane = tid & 63, wv = tid >> 6;
  const int wr = wv >> 1, wc = wv & 1;
  const int l15 = lane & 15, q8 = (lane >> 4) << 3, q4 = (lane >> 4) << 2;
  const int m0 = blockIdx.y * 64, n0 = blockIdx.x * 64;
  const int r0 = tid >> 3, c8 = (tid & 7) << 3;
  f32x4 acc[2][2];
#pragma unroll
  for (int t = 0; t < 2; ++t)
#pragma unroll
    for (int u = 0; u < 2; ++u)
#pragma unroll
      for (int r = 0; r < 4; ++r) acc[t][u][r] = 0.f;
  bf16x8 rA[2], rBh[2], rBl[2];
#define K5_LOAD(kt)                                                       \
  {                                                                       \
    _Pragma("unroll") for (int c = 0; c < 2; ++c) {                       \
      int row = c * 32 + r0;                                              \
      rA[c] = *(const bf16x8*)(A + (size_t)(m0 + row) * Dsz + (kt) + c8);   \
      rBh[c] = *(const bf16x8*)(Bh + (size_t)(n0 + row) * Dsz + (kt) + c8); \
      rBl[c] = *(const bf16x8*)(Bl + (size_t)(n0 + row) * Dsz + (kt) + c8); \
    }                                                                     \
  }
  K5_LOAD(0)
  for (int kt = 0; kt < Dsz; kt += 64) {
    __syncthreads();
#pragma unroll
    for (int c = 0; c < 2; ++c) {
      int row = c * 32 + r0;
      *(bf16x8*)&sA[row * LDT + c8] = rA[c];
      *(bf16x8*)&sBh[row * LDT + c8] = rBh[c];
      *(bf16x8*)&sBl[row * LDT + c8] = rBl[c];
    }
    __syncthreads();
    if (kt + 64 < Dsz) K5_LOAD(kt + 64)
#pragma unroll
    for (int ks = 0; ks < 64; ks += 32) {
      bf16x8 fa[2], fbh[2], fbl[2];
#pragma unroll
      for (int t = 0; t < 2; ++t) fa[t] = *(const bf16x8*)&sA[(wr * 32 + t * 16 + l15) * LDT + ks + q8];
#pragma unroll
      for (int u = 0; u < 2; ++u) {
        int n = wc * 32 + u * 16 + l15;
        fbh[u] = *(const bf16x8*)&sBh[n * LDT + ks + q8];
        fbl[u] = *(const bf16x8*)&sBl[n * LDT + ks + q8];
      }
#pragma unroll
      for (int t = 0; t < 2; ++t)
#pragma unroll
        for (int u = 0; u < 2; ++u) {
          acc[t][u] = MFMA(fa[t], fbh[u], acc[t][u]);
          acc[t][u] = MFMA(fa[t], fbl[u], acc[t][u]);
        }
    }
  }
#pragma unroll
  for (int t = 0; t < 2; ++t)
#pragma unroll
    for (int u = 0; u < 2; ++u) {
      int col = n0 + wc * 32 + u * 16 + l15;
#pragma unroll
      for (int r = 0; r < 4; ++r) {
        int row = m0 + wr * 32 + t * 16 + q4 + r;
        C[(size_t)row * Dsz + col] = acc[t][u][r];
      }
    }
#undef K5_LOAD
}

// ---------------------------------------------------------------------------
extern "C" void kernel_launch(void* const* d_in, const int* in_sizes, int n_in,
                              void* d_out, int out_size, void* d_ws, size_t ws_size,
                              hipStream_t stream) {
  const float* x      = (const float*)d_in[0];
  const float* qkv_w  = (const float*)d_in[1];
  const float* out_w  = (const float*)d_in[2];
  const float* bias_p = (const float*)d_in[3];
  const float* bias_a = (const float*)d_in[4];
  const float* w1     = (const float*)d_in[5];
  const float* b1     = (const float*)d_in[6];
  const float* w2     = (const float*)d_in[7];
  const float* b2     = (const float*)d_in[8];
  float* out = (float*)d_out;

  // ws layout (bytes). scores (64 MB) ALIASES x_h/w_h/w_l (dead after k1).
  char* ws = (char*)d_ws;
  const size_t MB = 1ull << 20;
  bf16* ow_h   = (bf16*)(ws + 0 * MB);            // 2 MB
  bf16* ow_l   = (bf16*)(ws + 2 * MB);            // 2 MB
  bf16* qkv_bf = (bf16*)(ws + 4 * MB);            // 12 MB
  bf16* v_t    = (bf16*)(ws + 16 * MB);           // 4 MB
  bf16* aout   = (bf16*)(ws + 20 * MB);           // 4 MB
  float* kbtt  = (float*)(ws + 24 * MB);          // 64 KB
  float* sums  = (float*)(ws + 24 * MB + 65536);  // 512 KB [b][i][h][chunk]
  bf16* wf     = (bf16*)(ws + 24 * MB + 589824);  // 2 KB
  float2* tk   = (float2*)(ws + 24 * MB + 655360);// 256 KB [o][n]
  bf16* x_h    = (bf16*)(ws + 25 * MB);           // 4 MB   (dead after k1)
  bf16* w_h    = (bf16*)(ws + 29 * MB);           // 6 MB   (dead after k1)
  bf16* w_l    = (bf16*)(ws + 35 * MB);           // 6 MB   (dead after k1)
  bf16* sc_bf  = (bf16*)(ws + 25 * MB);           // 64 MB, ends at 89 MB

  cast_hi<<<2048, 256, 0, stream>>>(x, x_h, Bsz * Ssz * Dsz);
  cast_hilo<<<3072, 256, 0, stream>>>(qkv_w, w_h, w_l, QKV3 * Dsz);
  cast_hilo<<<1024, 256, 0, stream>>>(out_w, ow_h, ow_l, Dsz * Dsz);
  kb_table<<<64, 256, 0, stream>>>(bias_p, bias_a, kbtt);
  tk_table<<<128, 256, 0, stream>>>(kbtt, w1, b1, tk);
  wfrag<<<1, 64, 0, stream>>>(w1, w2, wf);

  k1_qkv<<<dim3(QKV3 / 96, (Bsz * Ssz) / 128), 256, 0, stream>>>(x_h, w_h, w_l, qkv_bf);
  pack_vt<<<dim3(Ssz / 64, Bsz * Hn), 256, 0, stream>>>(qkv_bf, v_t);

  k2_qk<<<dim3(Ssz / 128, Ssz / 128, Bsz * Hn), 256, 0, stream>>>(qkv_bf, sc_bf);
  dape_softmax<<<dim3(4, Ssz, Bsz), 256, 0, stream>>>(sc_bf, tk, wf, b2, sums);
  k4_av<<<dim3(Ssz / 64, Hn, Bsz), 256, 0, stream>>>(sc_bf, v_t, sums, aout);

  k5_out<<<dim3(Dsz / 64, (Bsz * Ssz) / 64), 256, 0, stream>>>(aout, ow_h, ow_l, out);
}

// Round 11
// 202.893 us; speedup vs baseline: 1.1574x; 1.0724x over previous
//
#include <hip/hip_runtime.h>
#include <math.h>

#define Bsz 2
#define Ssz 1024
#define Dsz 1024
#define Hn 16
#define DHsz 64
#define QKV3 3072
#define SCALE 0.125f

typedef __bf16 bf16;
typedef bf16 bf16x8 __attribute__((ext_vector_type(8)));
typedef bf16 bf16x4 __attribute__((ext_vector_type(4)));
typedef float f32x4 __attribute__((ext_vector_type(4)));

#define MFMA(a, b, c) __builtin_amdgcn_mfma_f32_16x16x32_bf16(a, b, c, 0, 0, 0)
#define LDT 72

// ---------------------------------------------------------------------------
// cast fp32 -> bf16 (round-to-nearest). Prob-storage bf16 ulp (2^-9) dominates
// the error budget (absmax pinned at 1.95e-3 across r2-r10), so single-term
// bf16 GEMM operands are free.
// ---------------------------------------------------------------------------
__global__ void cast_hi(const float* __restrict__ src, bf16* __restrict__ hi, int n) {
  int idx = (blockIdx.x * 256 + threadIdx.x) * 4;
  if (idx >= n) return;
  float4 v = *(const float4*)(src + idx);
  bf16x4 hv = {(bf16)v.x, (bf16)v.y, (bf16)v.z, (bf16)v.w};
  *(bf16x4*)(hi + idx) = hv;
}

// kbtt[d][h] = -clip(p_h)*log1p(clip(a_h)*d)
__global__ void kb_table(const float* __restrict__ bias_p, const float* __restrict__ bias_a,
                         float* __restrict__ kbtt) {
  int idx = blockIdx.x * 256 + threadIdx.x;  // 16384
  int d = idx >> 4, h = idx & 15;
  float p = fmaxf(bias_p[h], 0.01f), a = fmaxf(bias_a[h], 0.01f);
  kbtt[idx] = -p * log1pf(a * (float)d);
}

// tk[o][n] = { b1[n] + sum_h w1[n][16+h]*kb(|o-1024|,h),  kb(|o-1024|,n) }
__global__ void tk_table(const float* __restrict__ kbtt, const float* __restrict__ w1,
                         const float* __restrict__ b1, float2* __restrict__ tk) {
  int idx = blockIdx.x * 256 + threadIdx.x;  // 32768
  int o = idx >> 4, n = idx & 15;
  int d = o - 1024; if (d < 0) d = -d; if (d > 1023) d = 1023;
  float t1 = b1[n];
#pragma unroll
  for (int h = 0; h < 16; ++h) t1 += w1[n * 32 + 16 + h] * kbtt[d * 16 + h];
  tk[idx] = make_float2(t1, kbtt[d * 16 + n]);
}

// Precompute dape MFMA weight fragments: wf[0..511]=w1d (hi|lo), wf[512..1023]=w2a
__global__ void wfrag(const float* __restrict__ w1, const float* __restrict__ w2,
                      bf16* __restrict__ wf) {
  int lane = threadIdx.x;  // 64
  int l15 = lane & 15, q8 = (lane >> 4) << 3;
  bf16x8 w1d, w2a;
#pragma unroll
  for (int e = 0; e < 8; ++e) {
    int k = q8 + e;
    if (k < 16) {
      w1d[e] = (bf16)w1[l15 * 32 + k];
    } else {
      float w = w1[l15 * 32 + k - 16];
      w1d[e] = (bf16)(w - (float)(bf16)w);
    }
    w2a[e] = (bf16)w2[l15 * 16 + (k & 15)];
  }
  *(bf16x8*)(wf + lane * 8) = w1d;
  *(bf16x8*)(wf + 512 + lane * 8) = w2a;
}

// ---------------------------------------------------------------------------
// K1: qkv_bf = bf16( x_h @ w_h^T )  1-term MFMA, tile 128x96 -> 512 blocks
// ---------------------------------------------------------------------------
__global__ __launch_bounds__(256, 3) void k1_qkv(const bf16* __restrict__ A,
                                                 const bf16* __restrict__ B,
                                                 bf16* __restrict__ C) {
  __shared__ __align__(16) bf16 sA[128 * LDT];
  __shared__ __align__(16) bf16 sB[96 * LDT];
  const int tid = threadIdx.x;
  const int lane = tid & 63, wv = tid >> 6;
  const int wr = wv >> 1, wc = wv & 1;
  const int l15 = lane & 15, q8 = (lane >> 4) << 3, q4 = (lane >> 4) << 2;
  const int m0 = blockIdx.y * 128, n0 = blockIdx.x * 96;
  const int r0 = tid >> 3, c8 = (tid & 7) << 3;

  f32x4 acc[4][3];
#pragma unroll
  for (int t = 0; t < 4; ++t)
#pragma unroll
    for (int u = 0; u < 3; ++u)
#pragma unroll
      for (int r = 0; r < 4; ++r) acc[t][u][r] = 0.f;

  bf16x8 rA[4], rB[3];
#define K1_LOAD(kt)                                                         \
  {                                                                         \
    _Pragma("unroll") for (int c = 0; c < 4; ++c)                           \
      rA[c] = *(const bf16x8*)(A + (size_t)(m0 + c * 32 + r0) * Dsz + (kt) + c8);  \
    _Pragma("unroll") for (int c = 0; c < 3; ++c)                           \
      rB[c] = *(const bf16x8*)(B + (size_t)(n0 + c * 32 + r0) * Dsz + (kt) + c8);  \
  }

  K1_LOAD(0)
  for (int kt = 0; kt < Dsz; kt += 64) {
    __syncthreads();
#pragma unroll
    for (int c = 0; c < 4; ++c) *(bf16x8*)&sA[(c * 32 + r0) * LDT + c8] = rA[c];
#pragma unroll
    for (int c = 0; c < 3; ++c) *(bf16x8*)&sB[(c * 32 + r0) * LDT + c8] = rB[c];
    __syncthreads();
    if (kt + 64 < Dsz) K1_LOAD(kt + 64)
#pragma unroll
    for (int ks = 0; ks < 64; ks += 32) {
      bf16x8 fa[4], fb[3];
#pragma unroll
      for (int t = 0; t < 4; ++t)
        fa[t] = *(const bf16x8*)&sA[(wr * 64 + t * 16 + l15) * LDT + ks + q8];
#pragma unroll
      for (int u = 0; u < 3; ++u)
        fb[u] = *(const bf16x8*)&sB[(wc * 48 + u * 16 + l15) * LDT + ks + q8];
#pragma unroll
      for (int t = 0; t < 4; ++t)
#pragma unroll
        for (int u = 0; u < 3; ++u) acc[t][u] = MFMA(fa[t], fb[u], acc[t][u]);
    }
  }
#pragma unroll
  for (int t = 0; t < 4; ++t)
#pragma unroll
    for (int u = 0; u < 3; ++u) {
      int col = n0 + wc * 48 + u * 16 + l15;
#pragma unroll
      for (int r = 0; r < 4; ++r) {
        int row = m0 + wr * 64 + t * 16 + q4 + r;
        C[(size_t)row * QKV3 + col] = (bf16)acc[t][u][r];
      }
    }
#undef K1_LOAD
}

// ---------------------------------------------------------------------------
// pack V transposed: v_t[b][h][d][j]
// ---------------------------------------------------------------------------
__global__ void pack_vt(const bf16* __restrict__ qkv, bf16* __restrict__ vt) {
  __shared__ __align__(16) bf16 T[64 * LDT];
  const int tid = threadIdx.x;
  const int bh = blockIdx.y, b = bh >> 4, h = bh & 15;
  const int j0 = blockIdx.x * 64;
#pragma unroll
  for (int c = 0; c < 2; ++c) {
    int lin = c * 256 + tid;
    int jr = lin >> 3, d8 = (lin & 7) << 3;
    bf16x8 v = *(const bf16x8*)(qkv + (size_t)(b * Ssz + j0 + jr) * QKV3 + 2048 + h * DHsz + d8);
#pragma unroll
    for (int e = 0; e < 8; ++e) T[(d8 + e) * LDT + jr] = v[e];
  }
  __syncthreads();
#pragma unroll
  for (int c = 0; c < 2; ++c) {
    int lin = c * 256 + tid;
    int d = lin >> 3, j8 = (lin & 7) << 3;
    bf16x8 o = *(const bf16x8*)&T[d * LDT + j8];
    *(bf16x8*)(vt + ((size_t)(b * Hn + h) * DHsz + d) * Ssz + j0 + j8) = o;
  }
}

// ---------------------------------------------------------------------------
// K2: scores_bf[b][h][i][j] = bf16( SCALE * Q @ K^T )   both batches, one launch
// ---------------------------------------------------------------------------
__global__ __launch_bounds__(256, 3) void k2_qk(const bf16* __restrict__ qkv,
                                                bf16* __restrict__ scores) {
  __shared__ __align__(16) bf16 sA[128 * LDT], sB[128 * LDT];
  const int tid = threadIdx.x;
  const int lane = tid & 63, wv = tid >> 6;
  const int wr = wv >> 1, wc = wv & 1;
  const int l15 = lane & 15, q8 = (lane >> 4) << 3, q4 = (lane >> 4) << 2;
  const int z = blockIdx.z, b = z >> 4, h = z & 15;
  const int i0 = blockIdx.y * 128, j0 = blockIdx.x * 128;
  const bf16* Ab = qkv + (size_t)b * Ssz * QKV3 + h * DHsz;
  const bf16* Bb = Ab + Ssz;
  const int r0 = tid >> 3, c8 = (tid & 7) << 3;
#pragma unroll
  for (int c = 0; c < 4; ++c) {
    int row = c * 32 + r0;
    *(bf16x8*)&sA[row * LDT + c8] = *(const bf16x8*)(Ab + (size_t)(i0 + row) * QKV3 + c8);
    *(bf16x8*)&sB[row * LDT + c8] = *(const bf16x8*)(Bb + (size_t)(j0 + row) * QKV3 + c8);
  }
  __syncthreads();
  f32x4 acc[4][4];
#pragma unroll
  for (int t = 0; t < 4; ++t)
#pragma unroll
    for (int u = 0; u < 4; ++u)
#pragma unroll
      for (int r = 0; r < 4; ++r) acc[t][u][r] = 0.f;
#pragma unroll
  for (int ks = 0; ks < 64; ks += 32) {
    bf16x8 fa[4], fb[4];
#pragma unroll
    for (int t = 0; t < 4; ++t) fa[t] = *(const bf16x8*)&sA[(wr * 64 + t * 16 + l15) * LDT + ks + q8];
#pragma unroll
    for (int u = 0; u < 4; ++u) fb[u] = *(const bf16x8*)&sB[(wc * 64 + u * 16 + l15) * LDT + ks + q8];
#pragma unroll
    for (int t = 0; t < 4; ++t)
#pragma unroll
      for (int u = 0; u < 4; ++u) acc[t][u] = MFMA(fa[t], fb[u], acc[t][u]);
  }
  bf16* dstp = scores + ((size_t)(b * Hn + h) << 20);
#pragma unroll
  for (int t = 0; t < 4; ++t)
#pragma unroll
    for (int u = 0; u < 4; ++u) {
      int col = j0 + wc * 64 + u * 16 + l15;
#pragma unroll
      for (int r = 0; r < 4; ++r) {
        int row = i0 + wr * 64 + t * 16 + q4 + r;
        dstp[((size_t)row << 10) + col] = (bf16)(acc[t][u][r] * SCALE);
      }
    }
}

// ---------------------------------------------------------------------------
// K3: DAPE MLP v4 — lgt + contiguous-write exp phase + tk table. (r10, unchanged)
// ---------------------------------------------------------------------------
__device__ __forceinline__ float gelu_fast(float x) {
  float z = fabsf(x) * 0.70710678118654752f;
  float t = __builtin_amdgcn_rcpf(fmaf(0.3275911f, z, 1.0f));
  float poly = t * fmaf(t, fmaf(t, fmaf(t, fmaf(t, 1.061405429f, -1.453152027f),
                                        1.421413741f), -0.284496736f), 0.254829592f);
  float erfa = 1.0f - poly * __expf(-z * z);
  float erfs = copysignf(erfa, x);
  return 0.5f * x * (1.0f + erfs);
}

#define SHS 264  // sH row stride (bf16)
#define LGS 264  // lgt row stride (fp32)

__global__ __launch_bounds__(256, 5) void dape_softmax(bf16* scores,
                                                       const float2* __restrict__ tk,
                                                       const bf16* __restrict__ wf,
                                                       const float* __restrict__ b2,
                                                       float* __restrict__ sums) {
  const int c = blockIdx.x;   // chunk 0..3 (256 j each)
  const int i = blockIdx.y;   // query row
  const int b = blockIdx.z;   // batch
  const int tid = threadIdx.x;
  const int lane = tid & 63, wv = tid >> 6;
  const int l15 = lane & 15, q = lane >> 4;
  const int q8 = q << 3, q4 = q << 2;

  __shared__ bf16 sH[Hn][SHS];                   // 8448 B raw bf16 scores
  __shared__ float lgt[Hn][LGS];                 // 16896 B logits
  __shared__ __align__(16) bf16 hdnS[4][16][40]; // 5120 B (cols 16..31 zeroed)

  const bf16x8 w1d = *(const bf16x8*)(wf + lane * 8);
  const bf16x8 w2a = *(const bf16x8*)(wf + 512 + lane * 8);
  const float bias2 = b2[l15];

  if (lane < 32) {
    int row = lane >> 1, col = 16 + (lane & 1) * 8;
    *(bf16x8*)&hdnS[wv][row][col] = (bf16x8){};
  }

  // ---- stage this wave's 64-j slice of all 16 head rows (bf16x8 copies) ----
  const int jw = wv * 64;
  const bf16* srow = scores + ((size_t)(b * Hn) << 20) + ((size_t)i << 10) + c * 256;
#pragma unroll
  for (int t = 0; t < 2; ++t) {
    int h = t * 8 + (lane >> 3);
    int col = jw + (lane & 7) * 8;
    *(bf16x8*)&sH[h][col] = *(const bf16x8*)(srow + ((size_t)h << 20) + col);
  }
  // no barrier: each wave touches only its own j-columns until the exp phase

  // tk pointer: o = (global j) - i + 1024, linear in j
  const float2* tkp = tk + ((size_t)(c * 256 + jw + q4 - i + 1024) << 4) + l15;

  for (int jt = 0; jt < 4; ++jt) {
    const int j0c = jw + jt * 16;
    bf16x8 a1;
#pragma unroll
    for (int e = 0; e < 8; ++e) a1[e] = sH[(q8 + e) & 15][j0c + l15];
    float2 tkv[4];
#pragma unroll
    for (int r = 0; r < 4; ++r) tkv[r] = tkp[r * 16];
    f32x4 c1 = {tkv[0].x, tkv[1].x, tkv[2].x, tkv[3].x};
    c1 = MFMA(a1, w1d, c1);
#pragma unroll
    for (int r = 0; r < 4; ++r) hdnS[wv][q4 + r][l15] = (bf16)gelu_fast(c1[r]);
    bf16x8 a2 = *(const bf16x8*)&hdnS[wv][l15][q8];
    f32x4 c2 = {bias2, bias2, bias2, bias2};
    c2 = MFMA(a2, w2a, c2);
    bf16x4 sc4 = *(const bf16x4*)&sH[l15][j0c + q4];
    f32x4 lg;
#pragma unroll
    for (int r = 0; r < 4; ++r) lg[r] = (float)sc4[r] + tkv[r].y + c2[r];
    *(f32x4*)&lgt[l15][j0c + q4] = lg;
    tkp += 256;  // +16 o
  }
  __syncthreads();

  // ---- exp (no max-sub; logits bounded) + partial sums, contiguous writes ----
#pragma unroll
  for (int hh = 0; hh < 4; ++hh) {
    const int h = wv * 4 + hh;
    f32x4 v0 = *(const f32x4*)&lgt[h][lane * 4];
    float s = 0.f;
#pragma unroll
    for (int e = 0; e < 4; ++e) { v0[e] = __expf(v0[e]); s += v0[e]; }
#pragma unroll
    for (int off = 32; off > 0; off >>= 1) s += __shfl_xor(s, off, 64);
    bf16* dst = scores + ((size_t)(b * Hn + h) << 20) + ((size_t)i << 10) + c * 256;
    bf16x4 p0 = {(bf16)v0[0], (bf16)v0[1], (bf16)v0[2], (bf16)v0[3]};
    *(bf16x4*)(dst + lane * 4) = p0;
    if (lane == 0) sums[((((b << 10) + i) << 4) + h) * 4 + c] = s;
  }
}

// ---------------------------------------------------------------------------
// K4: aout = (P_un @ V) / sum(chunks)   (via v_t), per (i-tile, h, b)
// ---------------------------------------------------------------------------
__global__ __launch_bounds__(256, 4) void k4_av(const bf16* __restrict__ attn,
                                                const bf16* __restrict__ vt,
                                                const float* __restrict__ sums,
                                                bf16* __restrict__ aout) {
  __shared__ __align__(16) bf16 sA[64 * LDT], sB[64 * LDT];
  const int tid = threadIdx.x;
  const int lane = tid & 63, wv = tid >> 6;
  const int wr = wv >> 1, wc = wv & 1;
  const int l15 = lane & 15, q8 = (lane >> 4) << 3, q4 = (lane >> 4) << 2;
  const int i0 = blockIdx.x * 64, h = blockIdx.y, b = blockIdx.z;
  const bf16* Ab = attn + ((size_t)(b * Hn + h) << 20) + ((size_t)i0 << 10);
  const bf16* Bb = vt + (size_t)(b * Hn + h) * DHsz * Ssz;
  const int r0 = tid >> 3, c8 = (tid & 7) << 3;
  f32x4 acc[2][2];
#pragma unroll
  for (int t = 0; t < 2; ++t)
#pragma unroll
    for (int u = 0; u < 2; ++u)
#pragma unroll
      for (int r = 0; r < 4; ++r) acc[t][u][r] = 0.f;
  bf16x8 rA[2], rB[2];
#define K4_LOAD(kt)                                               \
  {                                                               \
    _Pragma("unroll") for (int c = 0; c < 2; ++c) {               \
      int row = c * 32 + r0;                                      \
      rA[c] = *(const bf16x8*)(Ab + ((size_t)row << 10) + (kt) + c8); \
      rB[c] = *(const bf16x8*)(Bb + ((size_t)row << 10) + (kt) + c8); \
    }                                                             \
  }
  K4_LOAD(0)
  for (int kt = 0; kt < Ssz; kt += 64) {
    __syncthreads();
#pragma unroll
    for (int c = 0; c < 2; ++c) {
      int row = c * 32 + r0;
      *(bf16x8*)&sA[row * LDT + c8] = rA[c];
      *(bf16x8*)&sB[row * LDT + c8] = rB[c];
    }
    __syncthreads();
    if (kt + 64 < Ssz) K4_LOAD(kt + 64)
#pragma unroll
    for (int ks = 0; ks < 64; ks += 32) {
      bf16x8 fa[2], fb[2];
#pragma unroll
      for (int t = 0; t < 2; ++t) fa[t] = *(const bf16x8*)&sA[(wr * 32 + t * 16 + l15) * LDT + ks + q8];
#pragma unroll
      for (int u = 0; u < 2; ++u) fb[u] = *(const bf16x8*)&sB[(wc * 32 + u * 16 + l15) * LDT + ks + q8];
#pragma unroll
      for (int t = 0; t < 2; ++t)
#pragma unroll
        for (int u = 0; u < 2; ++u) acc[t][u] = MFMA(fa[t], fb[u], acc[t][u]);
    }
  }
#pragma unroll
  for (int t = 0; t < 2; ++t)
#pragma unroll
    for (int r = 0; r < 4; ++r) {
      int row = i0 + wr * 32 + t * 16 + q4 + r;
      f32x4 sv = *(const f32x4*)&sums[((((b << 10) + row) << 4) + h) * 4];
      float inv = 1.f / (sv[0] + sv[1] + sv[2] + sv[3]);
#pragma unroll
      for (int u = 0; u < 2; ++u) {
        int d = wc * 32 + u * 16 + l15;
        aout[(size_t)(b * Ssz + row) * Dsz + h * DHsz + d] = (bf16)(acc[t][u][r] * inv);
      }
    }
#undef K4_LOAD
}

// ---------------------------------------------------------------------------
// K5: out = aout_bf @ ow_h^T  1-term, fp32 out, tile 64x64 -> 512 blocks
// ---------------------------------------------------------------------------
__global__ __launch_bounds__(256, 4) void k5_out(const bf16* __restrict__ A,
                                                 const bf16* __restrict__ B,
                                                 float* __restrict__ C) {
  __shared__ __align__(16) bf16 sA[64 * LDT], sB[64 * LDT];
  const int tid = threadIdx.x;
  const int lane = tid & 63, wv = tid >> 6;
  const int wr = wv >> 1, wc = wv & 1;
  const int l15 = lane & 15, q8 = (lane >> 4) << 3, q4 = (lane >> 4) << 2;
  const int m0 = blockIdx.y * 64, n0 = blockIdx.x * 64;
  const int r0 = tid >> 3, c8 = (tid & 7) << 3;
  f32x4 acc[2][2];
#pragma unroll
  for (int t = 0; t < 2; ++t)
#pragma unroll
    for (int u = 0; u < 2; ++u)
#pragma unroll
      for (int r = 0; r < 4; ++r) acc[t][u][r] = 0.f;
  bf16x8 rA[2], rB[2];
#define K5_LOAD(kt)                                                       \
  {                                                                       \
    _Pragma("unroll") for (int c = 0; c < 2; ++c) {                       \
      int row = c * 32 + r0;                                              \
      rA[c] = *(const bf16x8*)(A + (size_t)(m0 + row) * Dsz + (kt) + c8);   \
      rB[c] = *(const bf16x8*)(B + (size_t)(n0 + row) * Dsz + (kt) + c8);   \
    }                                                                     \
  }
  K5_LOAD(0)
  for (int kt = 0; kt < Dsz; kt += 64) {
    __syncthreads();
#pragma unroll
    for (int c = 0; c < 2; ++c) {
      int row = c * 32 + r0;
      *(bf16x8*)&sA[row * LDT + c8] = rA[c];
      *(bf16x8*)&sB[row * LDT + c8] = rB[c];
    }
    __syncthreads();
    if (kt + 64 < Dsz) K5_LOAD(kt + 64)
#pragma unroll
    for (int ks = 0; ks < 64; ks += 32) {
      bf16x8 fa[2], fb[2];
#pragma unroll
      for (int t = 0; t < 2; ++t) fa[t] = *(const bf16x8*)&sA[(wr * 32 + t * 16 + l15) * LDT + ks + q8];
#pragma unroll
      for (int u = 0; u < 2; ++u) fb[u] = *(const bf16x8*)&sB[(wc * 32 + u * 16 + l15) * LDT + ks + q8];
#pragma unroll
      for (int t = 0; t < 2; ++t)
#pragma unroll
        for (int u = 0; u < 2; ++u) acc[t][u] = MFMA(fa[t], fb[u], acc[t][u]);
    }
  }
#pragma unroll
  for (int t = 0; t < 2; ++t)
#pragma unroll
    for (int u = 0; u < 2; ++u) {
      int col = n0 + wc * 32 + u * 16 + l15;
#pragma unroll
      for (int r = 0; r < 4; ++r) {
        int row = m0 + wr * 32 + t * 16 + q4 + r;
        C[(size_t)row * Dsz + col] = acc[t][u][r];
      }
    }
#undef K5_LOAD
}

// ---------------------------------------------------------------------------
extern "C" void kernel_launch(void* const* d_in, const int* in_sizes, int n_in,
                              void* d_out, int out_size, void* d_ws, size_t ws_size,
                              hipStream_t stream) {
  const float* x      = (const float*)d_in[0];
  const float* qkv_w  = (const float*)d_in[1];
  const float* out_w  = (const float*)d_in[2];
  const float* bias_p = (const float*)d_in[3];
  const float* bias_a = (const float*)d_in[4];
  const float* w1     = (const float*)d_in[5];
  const float* b1     = (const float*)d_in[6];
  const float* w2     = (const float*)d_in[7];
  const float* b2     = (const float*)d_in[8];
  float* out = (float*)d_out;

  // ws layout (bytes). scores (64 MB) ALIASES x_h/w_h (dead after k1).
  char* ws = (char*)d_ws;
  const size_t MB = 1ull << 20;
  bf16* ow_h   = (bf16*)(ws + 0 * MB);            // 2 MB
  bf16* qkv_bf = (bf16*)(ws + 2 * MB);            // 12 MB
  bf16* v_t    = (bf16*)(ws + 14 * MB);           // 4 MB
  bf16* aout   = (bf16*)(ws + 18 * MB);           // 4 MB
  float* kbtt  = (float*)(ws + 22 * MB);          // 64 KB
  float* sums  = (float*)(ws + 22 * MB + 65536);  // 512 KB [b][i][h][chunk]
  bf16* wf     = (bf16*)(ws + 22 * MB + 589824);  // 2 KB
  float2* tk   = (float2*)(ws + 22 * MB + 655360);// 256 KB [o][n]
  bf16* x_h    = (bf16*)(ws + 23 * MB);           // 4 MB   (dead after k1)
  bf16* w_h    = (bf16*)(ws + 27 * MB);           // 6 MB   (dead after k1)
  bf16* sc_bf  = (bf16*)(ws + 23 * MB);           // 64 MB, ends at 87 MB

  cast_hi<<<2048, 256, 0, stream>>>(x, x_h, Bsz * Ssz * Dsz);
  cast_hi<<<3072, 256, 0, stream>>>(qkv_w, w_h, QKV3 * Dsz);
  cast_hi<<<1024, 256, 0, stream>>>(out_w, ow_h, Dsz * Dsz);
  kb_table<<<64, 256, 0, stream>>>(bias_p, bias_a, kbtt);
  tk_table<<<128, 256, 0, stream>>>(kbtt, w1, b1, tk);
  wfrag<<<1, 64, 0, stream>>>(w1, w2, wf);

  k1_qkv<<<dim3(QKV3 / 96, (Bsz * Ssz) / 128), 256, 0, stream>>>(x_h, w_h, qkv_bf);
  pack_vt<<<dim3(Ssz / 64, Bsz * Hn), 256, 0, stream>>>(qkv_bf, v_t);

  k2_qk<<<dim3(Ssz / 128, Ssz / 128, Bsz * Hn), 256, 0, stream>>>(qkv_bf, sc_bf);
  dape_softmax<<<dim3(4, Ssz, Bsz), 256, 0, stream>>>(sc_bf, tk, wf, b2, sums);
  k4_av<<<dim3(Ssz / 64, Hn, Bsz), 256, 0, stream>>>(sc_bf, v_t, sums, aout);

  k5_out<<<dim3(Dsz / 64, (Bsz * Ssz) / 64), 256, 0, stream>>>(aout, ow_h, out);
}